// Round 1
// baseline (207.422 us; speedup 1.0000x reference)
//
#include <hip/hip_runtime.h>
#include <math.h>

#define BB 32
#define SS 4096
#define DD 1024
#define CHUNKS 64                      // S-chunks per batch
#define ROWS_PER_CHUNK (SS / CHUNKS)   // 64
#define NBLK2 (BB * CHUNKS)            // 2048

__device__ __forceinline__ float wave_reduce_sum(float v) {
    #pragma unroll
    for (int off = 32; off > 0; off >>= 1)
        v += __shfl_xor(v, off, 64);
    return v;
}

__device__ __forceinline__ float dot4(float4 a, float4 b) {
    return a.x * b.x + a.y * b.y + a.z * b.z + a.w * b.w;
}

// K1: dec_att[b,d] = sum_k dec[b,k] * Win[d,k]   (x @ W.T)
__global__ __launch_bounds__(256) void k1_decatt(const float* __restrict__ dec,
                                                 const float* __restrict__ Win,
                                                 float* __restrict__ dec_att) {
    const int wid = threadIdx.x >> 6, lane = threadIdx.x & 63;
    const int d = blockIdx.x * 4 + wid;          // 256 blocks -> 1024 d
    const float4* Wrow = (const float4*)(Win + (size_t)d * DD);
    float4 w4[4];
    #pragma unroll
    for (int i = 0; i < 4; ++i) w4[i] = Wrow[lane + i * 64];
    for (int b = 0; b < BB; ++b) {
        const float4* x = (const float4*)(dec + (size_t)b * DD);
        float p = 0.f;
        #pragma unroll
        for (int i = 0; i < 4; ++i) p += dot4(w4[i], x[lane + i * 64]);
        p = wave_reduce_sum(p);
        if (lane == 0) dec_att[(size_t)b * DD + d] = p;
    }
}

// K2: single-pass online-softmax scan over enc rows.
// Writes raw scores into the weights output region, and per-(b,chunk)
// partial (m, l, acc[D]) into workspace.
__global__ __launch_bounds__(256) void k2_scan(const float* __restrict__ enc,
                                               const float* __restrict__ dec_att,
                                               float* __restrict__ scores,
                                               float* __restrict__ pacc,
                                               float* __restrict__ pml) {
    const int wid = threadIdx.x >> 6, lane = threadIdx.x & 63;
    const int b = blockIdx.x / CHUNKS, chunk = blockIdx.x % CHUNKS;
    const int s0 = chunk * ROWS_PER_CHUNK;

    const float4* q = (const float4*)(dec_att + (size_t)b * DD);
    float4 q4[4];
    #pragma unroll
    for (int i = 0; i < 4; ++i) q4[i] = q[lane + i * 64];

    float m = -1e30f, l = 0.f;
    float4 a4[4];
    #pragma unroll
    for (int i = 0; i < 4; ++i) a4[i] = make_float4(0.f, 0.f, 0.f, 0.f);

    const float4* encb = (const float4*)(enc + ((size_t)b * SS + s0) * DD);
    for (int r = wid; r < ROWS_PER_CHUNK; r += 4) {
        const float4* row = encb + (size_t)r * (DD / 4);
        float4 e4[4];
        #pragma unroll
        for (int i = 0; i < 4; ++i) e4[i] = row[lane + i * 64];
        float p = 0.f;
        #pragma unroll
        for (int i = 0; i < 4; ++i) p += dot4(q4[i], e4[i]);
        p = wave_reduce_sum(p);
        if (lane == 0) scores[(size_t)b * SS + s0 + r] = p;
        const float mn = fmaxf(m, p);
        const float sc = __expf(m - mn);
        const float w  = __expf(p - mn);
        l = l * sc + w;
        #pragma unroll
        for (int i = 0; i < 4; ++i) {
            a4[i].x = a4[i].x * sc + w * e4[i].x;
            a4[i].y = a4[i].y * sc + w * e4[i].y;
            a4[i].z = a4[i].z * sc + w * e4[i].z;
            a4[i].w = a4[i].w * sc + w * e4[i].w;
        }
        m = mn;
    }

    // Deterministic 4-wave combine via LDS (no float atomics).
    __shared__ float m_s[4], l_s[4];
    __shared__ __align__(16) float accbuf[DD];
    if (lane == 0) { m_s[wid] = m; l_s[wid] = l; }
    for (int t = threadIdx.x; t < DD; t += 256) accbuf[t] = 0.f;
    __syncthreads();
    const float m_b = fmaxf(fmaxf(m_s[0], m_s[1]), fmaxf(m_s[2], m_s[3]));
    const float f = __expf(m - m_b);
    const float l_b = l_s[0] * __expf(m_s[0] - m_b) + l_s[1] * __expf(m_s[1] - m_b)
                    + l_s[2] * __expf(m_s[2] - m_b) + l_s[3] * __expf(m_s[3] - m_b);
    for (int w = 0; w < 4; ++w) {
        if (wid == w) {
            #pragma unroll
            for (int i = 0; i < 4; ++i) {
                const int base = i * 256 + lane * 4;
                accbuf[base + 0] += a4[i].x * f;
                accbuf[base + 1] += a4[i].y * f;
                accbuf[base + 2] += a4[i].z * f;
                accbuf[base + 3] += a4[i].w * f;
            }
        }
        __syncthreads();
    }
    float4* outp = (float4*)(pacc + (size_t)blockIdx.x * DD);
    const float4* ab4 = (const float4*)accbuf;
    for (int t = threadIdx.x; t < DD / 4; t += 256) outp[t] = ab4[t];
    if (threadIdx.x == 0) {
        pml[(size_t)blockIdx.x * 2 + 0] = m_b;
        pml[(size_t)blockIdx.x * 2 + 1] = l_b;
    }
}

// K3: combine chunk partials -> weighted[b,:], global (m,l) per b.
__global__ __launch_bounds__(256) void k3_combine(const float* __restrict__ pacc,
                                                  const float* __restrict__ pml,
                                                  float* __restrict__ weighted,
                                                  float* __restrict__ mlglob) {
    const int b = blockIdx.x, t = threadIdx.x;
    float mg = -1e30f;
    for (int c = 0; c < CHUNKS; ++c) mg = fmaxf(mg, pml[(size_t)(b * CHUNKS + c) * 2]);
    float lg = 0.f;
    for (int c = 0; c < CHUNKS; ++c)
        lg += pml[(size_t)(b * CHUNKS + c) * 2 + 1] * __expf(pml[(size_t)(b * CHUNKS + c) * 2] - mg);
    float4 acc = make_float4(0.f, 0.f, 0.f, 0.f);
    for (int c = 0; c < CHUNKS; ++c) {
        const float fct = __expf(pml[(size_t)(b * CHUNKS + c) * 2] - mg);
        const float4 v = ((const float4*)(pacc + (size_t)(b * CHUNKS + c) * DD))[t];
        acc.x += v.x * fct; acc.y += v.y * fct; acc.z += v.z * fct; acc.w += v.w * fct;
    }
    const float inv = 1.f / lg;
    ((float4*)(weighted + (size_t)b * DD))[t] =
        make_float4(acc.x * inv, acc.y * inv, acc.z * inv, acc.w * inv);
    if (t == 0) { mlglob[b * 2] = mg; mlglob[b * 2 + 1] = lg; }
}

// K4: normalize raw scores in place -> softmax weights output.
__global__ __launch_bounds__(256) void k4_norm(float* __restrict__ wts,
                                               const float* __restrict__ mlglob) {
    const int idx = blockIdx.x * 256 + threadIdx.x;  // B*S total
    const int b = idx >> 12;                          // / 4096
    const float mg = mlglob[b * 2], lg = mlglob[b * 2 + 1];
    wts[idx] = __expf(wts[idx] - mg) / lg;
}

// K5: out[b,d] = tanh( [weighted, dec] . Wout[d,:] ), Wout row-major [D, 2D]
__global__ __launch_bounds__(256) void k5_out(const float* __restrict__ weighted,
                                              const float* __restrict__ dec,
                                              const float* __restrict__ Wout,
                                              float* __restrict__ out) {
    const int wid = threadIdx.x >> 6, lane = threadIdx.x & 63;
    const int d = blockIdx.x * 4 + wid;  // 256 blocks -> 1024 d
    const float4* Wrow = (const float4*)(Wout + (size_t)d * (2 * DD));
    float4 w4[8];
    #pragma unroll
    for (int i = 0; i < 8; ++i) w4[i] = Wrow[lane + i * 64];
    for (int b = 0; b < BB; ++b) {
        const float4* xw = (const float4*)(weighted + (size_t)b * DD);
        const float4* xd = (const float4*)(dec + (size_t)b * DD);
        float p = 0.f;
        #pragma unroll
        for (int i = 0; i < 4; ++i) p += dot4(w4[i], xw[lane + i * 64]);
        #pragma unroll
        for (int i = 0; i < 4; ++i) p += dot4(w4[i + 4], xd[lane + i * 64]);
        p = wave_reduce_sum(p);
        if (lane == 0) out[(size_t)b * DD + d] = tanhf(p);
    }
}

extern "C" void kernel_launch(void* const* d_in, const int* in_sizes, int n_in,
                              void* d_out, int out_size, void* d_ws, size_t ws_size,
                              hipStream_t stream) {
    (void)in_sizes; (void)n_in; (void)out_size; (void)ws_size;
    const float* dec  = (const float*)d_in[0];   // [B, D]
    const float* enc  = (const float*)d_in[1];   // [B, S, D]
    const float* Win  = (const float*)d_in[2];   // [D, D]
    const float* Wout = (const float*)d_in[3];   // [D, 2D]

    float* out_final = (float*)d_out;            // [B, D]
    float* out_wts   = out_final + (size_t)BB * DD;  // [B, S]

    // workspace layout (floats)
    float* ws      = (float*)d_ws;
    float* dec_att = ws;                                  // B*D
    float* pacc    = dec_att + (size_t)BB * DD;           // NBLK2*D
    float* pml     = pacc + (size_t)NBLK2 * DD;           // NBLK2*2
    float* weighted= pml + (size_t)NBLK2 * 2;             // B*D
    float* mlglob  = weighted + (size_t)BB * DD;          // B*2

    hipLaunchKernelGGL(k1_decatt, dim3(DD / 4), dim3(256), 0, stream, dec, Win, dec_att);
    hipLaunchKernelGGL(k2_scan, dim3(NBLK2), dim3(256), 0, stream, enc, dec_att, out_wts, pacc, pml);
    hipLaunchKernelGGL(k3_combine, dim3(BB), dim3(256), 0, stream, pacc, pml, weighted, mlglob);
    hipLaunchKernelGGL(k4_norm, dim3(BB * SS / 256), dim3(256), 0, stream, out_wts, mlglob);
    hipLaunchKernelGGL(k5_out, dim3(DD / 4), dim3(256), 0, stream, weighted, dec, Wout, out_final);
}